// Round 1
// 935.324 us; speedup vs baseline: 1.2411x; 1.2411x over previous
//
#include <hip/hip_runtime.h>
#include <hip/hip_bf16.h>
#include <cstdint>
#include <cstddef>

typedef __bf16 bf16x8 __attribute__((ext_vector_type(8)));
typedef float  f32x4  __attribute__((ext_vector_type(4)));

static constexpr int TOK  = 4096;            // B*S
static constexpr int H    = 2048;
static constexpr int E    = 8;
static constexpr int IDIM = 1024;
static constexpr int ISD  = 4096;
static constexpr int MAXTILES = 72;          // >= max padded 128-row tiles (<=71)
static constexpr int MAXROWS  = MAXTILES * 128;  // 9216 >= 2*TOK + 8*127 padded

// meta layout (ints):
//  [0]      bf16-input flag
//  [4..11]  cnt[e]      (token count per expert)
//  [12..19] cursor[e]   (scatter cursors)
//  [20]     nTiles
//  [24..32] segStart[e] (padded prefix, segStart[8] = total padded rows)
//  [64..135]  tileExpert[t]
//  [136..207] tileBase[t]  (padded row offset of tile t)

// async global->LDS, 16B/lane; LDS dest = wave-uniform base + lane*16
__device__ __forceinline__ void gll16(const void* g, void* l) {
  __builtin_amdgcn_global_load_lds((const __attribute__((address_space(1))) void*)g,
                                   (__attribute__((address_space(3))) void*)l, 16, 0, 0);
}

__device__ __forceinline__ unsigned short f2bf(float f) {  // RNE fp32->bf16
  unsigned int u = __float_as_uint(f);
  u = (u + 0x7fffu + ((u >> 16) & 1u)) >> 16;
  return (unsigned short)u;
}

// ---- dtype detection + meta zeroing ----
__global__ __launch_bounds__(256) void detect_kernel(const unsigned int* __restrict__ x,
                                                     int* __restrict__ meta) {
  __shared__ int sh[256];
  const int tid = threadIdx.x;
  int c = 0;
  for (int i = tid; i < 1024; i += 256) {
    const unsigned int e = (x[i] >> 7) & 0xFFu;
    c += (e >= 100u && e <= 150u) ? 1 : 0;
  }
  sh[tid] = c;
  if (tid >= 4 && tid < 24) meta[tid] = 0;   // zero cnt[] and cursor[]
  __syncthreads();
  if (tid == 0) {
    int s = 0;
    for (int i = 0; i < 256; ++i) s += sh[i];
    meta[0] = (s > 512) ? 1 : 0;   // 1 => inputs bf16; 0 => fp32
  }
}

// ---- fp32 -> bf16 conversion (no-op when inputs already bf16) ----
__global__ __launch_bounds__(256) void convert_kernel(const float* __restrict__ src,
                                                      unsigned short* __restrict__ dst,
                                                      int n4, const int* __restrict__ flag) {
  if (*flag) return;
  int i = blockIdx.x * 256 + threadIdx.x;
  const int stride = gridDim.x * 256;
  for (; i < n4; i += stride) {
    const float4 v = ((const float4*)src)[i];
    ushort4 o;
    o.x = f2bf(v.x); o.y = f2bf(v.y); o.z = f2bf(v.z); o.w = f2bf(v.w);
    ((ushort4*)dst)[i] = o;
  }
}

// ---- router: fp32 logits, top-2, sigmoid, per-expert counting ----
__global__ __launch_bounds__(256) void router_kernel(
    const void* __restrict__ x_, const void* __restrict__ rw_,
    void* __restrict__ out, float* __restrict__ scale,
    int* __restrict__ meta, int* __restrict__ topk)
{
  const int bfmode = meta[0];
  const int t   = blockIdx.x;
  const int tid = threadIdx.x;
  const int l   = tid & 63, w = tid >> 6;
  const int off = tid * 8;

  float xs[8];
  if (bfmode) {
    bf16x8 v = *(const bf16x8*)((const unsigned short*)x_ + (size_t)t * H + off);
#pragma unroll
    for (int j = 0; j < 8; ++j) xs[j] = (float)v[j];
  } else {
    const float* xr = (const float*)x_ + (size_t)t * H + off;
    const float4 a = *(const float4*)xr;
    const float4 b = *(const float4*)(xr + 4);
    xs[0]=a.x; xs[1]=a.y; xs[2]=a.z; xs[3]=a.w; xs[4]=b.x; xs[5]=b.y; xs[6]=b.z; xs[7]=b.w;
  }

  float p[E];
#pragma unroll
  for (int e = 0; e < E; ++e) {
    float wv[8];
    if (bfmode) {
      bf16x8 v = *(const bf16x8*)((const unsigned short*)rw_ + (size_t)e * H + off);
#pragma unroll
      for (int j = 0; j < 8; ++j) wv[j] = (float)v[j];
    } else {
      const float* wr = (const float*)rw_ + (size_t)e * H + off;
      const float4 a = *(const float4*)wr;
      const float4 b = *(const float4*)(wr + 4);
      wv[0]=a.x; wv[1]=a.y; wv[2]=a.z; wv[3]=a.w; wv[4]=b.x; wv[5]=b.y; wv[6]=b.z; wv[7]=b.w;
    }
    float s = 0.f;
#pragma unroll
    for (int j = 0; j < 8; ++j) s = fmaf(xs[j], wv[j], s);
    p[e] = s;
  }
#pragma unroll
  for (int e = 0; e < E; ++e)
    for (int o = 32; o > 0; o >>= 1) p[e] += __shfl_down(p[e], o);

  __shared__ float red[E][4];
  __shared__ float lg[E];
  __shared__ float sres[2];
  __shared__ int   ires[2];
  if (l == 0) {
#pragma unroll
    for (int e = 0; e < E; ++e) red[e][w] = p[e];
  }
  __syncthreads();
  if (tid < E) {
    const float v = red[tid][0] + red[tid][1] + red[tid][2] + red[tid][3];
    lg[tid] = v;
    const size_t oi = (size_t)TOK * H + (size_t)t * E + tid;
    if (bfmode) ((unsigned short*)out)[oi] = f2bf(v);
    else        ((float*)out)[oi] = v;
  }
  __syncthreads();
  if (tid == 0) {
    int i0 = 0; float v0 = lg[0];
    for (int e = 1; e < E; ++e) if (lg[e] > v0) { v0 = lg[e]; i0 = e; }
    int i1 = -1; float v1 = 0.f; bool init = false;
    for (int e = 0; e < E; ++e) {
      if (e == i0) continue;
      if (!init || lg[e] > v1) { v1 = lg[e]; i1 = e; init = true; }
    }
    sres[0] = 1.f / (1.f + expf(-v0)); ires[0] = i0;
    sres[1] = 1.f / (1.f + expf(-v1)); ires[1] = i1;
    topk[2 * t + 0] = i0;
    topk[2 * t + 1] = i1;
    atomicAdd(&meta[4 + i0], 1);
    atomicAdd(&meta[4 + i1], 1);
  }
  __syncthreads();
  if (tid < E) {
    float s = 0.f;
    if (tid == ires[0]) s = sres[0];
    else if (tid == ires[1]) s = sres[1];
    scale[(size_t)t * E + tid] = s;
  }
}

// ---- tiny scan: padded segment starts + tile map; zero token list ----
__global__ __launch_bounds__(256) void scan_kernel(int* __restrict__ meta,
                                                   int* __restrict__ list) {
  const int tid = threadIdx.x;
  if (tid == 0) {
    int s = 0, nt = 0;
    for (int e = 0; e < E; ++e) {
      meta[24 + e] = s;
      const int cnt = meta[4 + e];
      const int tiles = (cnt + 127) >> 7;
      for (int i = 0; i < tiles; ++i) {
        meta[64 + nt]  = e;
        meta[136 + nt] = s + i * 128;
        ++nt;
      }
      s += tiles << 7;
    }
    meta[32] = s;    // total padded rows
    meta[20] = nt;   // total tiles
  }
  for (int i = tid; i < MAXROWS; i += 256) list[i] = 0;  // pad rows -> token 0
}

// ---- scatter token ids into per-expert padded lists ----
__global__ __launch_bounds__(256) void scatter_kernel(int* __restrict__ meta,
                                                      const int* __restrict__ topk,
                                                      int* __restrict__ list,
                                                      int* __restrict__ tokpos) {
  const int t = blockIdx.x * 256 + threadIdx.x;
  if (t >= TOK) return;
#pragma unroll
  for (int k = 0; k < 2; ++k) {
    const int e = topk[2 * t + k];
    const int p = atomicAdd(&meta[12 + e], 1);
    const int g = meta[24 + e] + p;
    list[g] = t;
    tokpos[2 * t + k] = g;
  }
}

// ---- shared-expert gate+up: hmid_sh = silu(x.sgw^T) * (x.suw^T) ----
// grid: x = token-tile (32, fastest), y = col-tile (ISD/64 = 64)
__global__ __launch_bounds__(256) void gateup_shared_kernel(
    const void* __restrict__ xo_,  const unsigned short* __restrict__ cx,
    const void* __restrict__ sgo_, const unsigned short* __restrict__ csgw,
    const void* __restrict__ suo_, const unsigned short* __restrict__ csuw,
    unsigned short* __restrict__ hmid_sh, const int* __restrict__ meta)
{
  const int bfmode = meta[0];
  const unsigned short* x       = bfmode ? (const unsigned short*)xo_  : cx;
  const unsigned short* sgate_w = bfmode ? (const unsigned short*)sgo_ : csgw;
  const unsigned short* sup_w   = bfmode ? (const unsigned short*)suo_ : csuw;

  __shared__ __attribute__((aligned(16))) unsigned short As[128 * 64];
  __shared__ __attribute__((aligned(16))) unsigned short Bgs[64 * 64];
  __shared__ __attribute__((aligned(16))) unsigned short Bus[64 * 64];

  const int tid = threadIdx.x;
  const int l = tid & 63, w = tid >> 6;
  const int m0 = blockIdx.x * 128;
  const int jb = blockIdx.y * 64;

  const unsigned short* gB = sgate_w + (size_t)jb * H;
  const unsigned short* uB = sup_w   + (size_t)jb * H;

  f32x4 accg[4][2] = {};
  f32x4 accu[4][2] = {};
  const int wm = (w >> 1) * 64;
  const int wn = (w & 1) * 32;
  const int quad = l >> 4, lm = l & 15;

  for (int k0 = 0; k0 < H; k0 += 64) {
#pragma unroll
    for (int j = 0; j < 4; ++j) {
      const int g = j * 256 + tid;
      const int r = g >> 3, c = g & 7;
      const int cc = c ^ (r & 7);
      gll16(x + (size_t)(m0 + r) * H + k0 + cc * 8, &As[g * 8]);
    }
#pragma unroll
    for (int j = 0; j < 2; ++j) {
      const int g = j * 256 + tid;
      const int r = g >> 3, c = g & 7;
      const int cc = c ^ (r & 7);
      gll16(gB + (size_t)r * H + k0 + cc * 8, &Bgs[g * 8]);
      gll16(uB + (size_t)r * H + k0 + cc * 8, &Bus[g * 8]);
    }
    __syncthreads();
#pragma unroll
    for (int ks = 0; ks < 64; ks += 32) {
      const int kc  = (ks >> 3) + quad;
      const int csw = (kc ^ (lm & 7)) * 8;
      bf16x8 a[4], bg[2], bu[2];
#pragma unroll
      for (int mt = 0; mt < 4; ++mt)
        a[mt] = *(const bf16x8*)&As[(wm + mt * 16 + lm) * 64 + csw];
#pragma unroll
      for (int nt = 0; nt < 2; ++nt) {
        bg[nt] = *(const bf16x8*)&Bgs[(wn + nt * 16 + lm) * 64 + csw];
        bu[nt] = *(const bf16x8*)&Bus[(wn + nt * 16 + lm) * 64 + csw];
      }
#pragma unroll
      for (int mt = 0; mt < 4; ++mt)
#pragma unroll
        for (int nt = 0; nt < 2; ++nt) {
          accg[mt][nt] = __builtin_amdgcn_mfma_f32_16x16x32_bf16(a[mt], bg[nt], accg[mt][nt], 0, 0, 0);
          accu[mt][nt] = __builtin_amdgcn_mfma_f32_16x16x32_bf16(a[mt], bu[nt], accu[mt][nt], 0, 0, 0);
        }
    }
    __syncthreads();
  }

#pragma unroll
  for (int mt = 0; mt < 4; ++mt) {
#pragma unroll
    for (int r = 0; r < 4; ++r) {
      const int t = m0 + wm + mt * 16 + quad * 4 + r;
#pragma unroll
      for (int nt = 0; nt < 2; ++nt) {
        const int j = jb + wn + nt * 16 + lm;
        const float g = accg[mt][nt][r];
        const float u = accu[mt][nt][r];
        const float hm = (g / (1.f + expf(-g))) * u;
        hmid_sh[(size_t)t * ISD + j] = f2bf(hm);
      }
    }
  }
}

// ---- routed gate+up over gathered token lists (top-2 sparsity) ----
// grid: x = padded row-tile (MAXTILES, early-exit), y = col-tile (IDIM/64 = 16)
__global__ __launch_bounds__(256) void gateup_routed_kernel(
    const void* __restrict__ xo_,  const unsigned short* __restrict__ cx,
    const void* __restrict__ gwo_, const unsigned short* __restrict__ cgw,
    const void* __restrict__ uwo_, const unsigned short* __restrict__ cuw,
    const float* __restrict__ scale, const int* __restrict__ list,
    unsigned short* __restrict__ hmid_r, const int* __restrict__ meta)
{
  if ((int)blockIdx.x >= meta[20]) return;
  const int bfmode = meta[0];
  const unsigned short* x      = bfmode ? (const unsigned short*)xo_  : cx;
  const unsigned short* gate_w = bfmode ? (const unsigned short*)gwo_ : cgw;
  const unsigned short* up_w   = bfmode ? (const unsigned short*)uwo_ : cuw;

  __shared__ __attribute__((aligned(16))) unsigned short As[128 * 64];
  __shared__ __attribute__((aligned(16))) unsigned short Bgs[64 * 64];
  __shared__ __attribute__((aligned(16))) unsigned short Bus[64 * 64];

  const int tid = threadIdx.x;
  const int l = tid & 63, w = tid >> 6;
  const int e    = meta[64 + blockIdx.x];
  const int base = meta[136 + blockIdx.x];
  const int jj   = blockIdx.y * 64;

  const unsigned short* gB = gate_w + ((size_t)e * IDIM + jj) * H;
  const unsigned short* uB = up_w   + ((size_t)e * IDIM + jj) * H;

  // gathered A-row tokens for this thread's 4 staging loads (reused every k0)
  int tok[4];
#pragma unroll
  for (int j = 0; j < 4; ++j) tok[j] = list[base + ((j * 256 + tid) >> 3)];

  f32x4 accg[4][2] = {};
  f32x4 accu[4][2] = {};
  const int wm = (w >> 1) * 64;
  const int wn = (w & 1) * 32;
  const int quad = l >> 4, lm = l & 15;

  for (int k0 = 0; k0 < H; k0 += 64) {
#pragma unroll
    for (int j = 0; j < 4; ++j) {
      const int g = j * 256 + tid;
      const int r = g >> 3, c = g & 7;
      const int cc = c ^ (r & 7);
      gll16(x + (size_t)tok[j] * H + k0 + cc * 8, &As[g * 8]);
    }
#pragma unroll
    for (int j = 0; j < 2; ++j) {
      const int g = j * 256 + tid;
      const int r = g >> 3, c = g & 7;
      const int cc = c ^ (r & 7);
      gll16(gB + (size_t)r * H + k0 + cc * 8, &Bgs[g * 8]);
      gll16(uB + (size_t)r * H + k0 + cc * 8, &Bus[g * 8]);
    }
    __syncthreads();
#pragma unroll
    for (int ks = 0; ks < 64; ks += 32) {
      const int kc  = (ks >> 3) + quad;
      const int csw = (kc ^ (lm & 7)) * 8;
      bf16x8 a[4], bg[2], bu[2];
#pragma unroll
      for (int mt = 0; mt < 4; ++mt)
        a[mt] = *(const bf16x8*)&As[(wm + mt * 16 + lm) * 64 + csw];
#pragma unroll
      for (int nt = 0; nt < 2; ++nt) {
        bg[nt] = *(const bf16x8*)&Bgs[(wn + nt * 16 + lm) * 64 + csw];
        bu[nt] = *(const bf16x8*)&Bus[(wn + nt * 16 + lm) * 64 + csw];
      }
#pragma unroll
      for (int mt = 0; mt < 4; ++mt)
#pragma unroll
        for (int nt = 0; nt < 2; ++nt) {
          accg[mt][nt] = __builtin_amdgcn_mfma_f32_16x16x32_bf16(a[mt], bg[nt], accg[mt][nt], 0, 0, 0);
          accu[mt][nt] = __builtin_amdgcn_mfma_f32_16x16x32_bf16(a[mt], bu[nt], accu[mt][nt], 0, 0, 0);
        }
    }
    __syncthreads();
  }

#pragma unroll
  for (int mt = 0; mt < 4; ++mt) {
#pragma unroll
    for (int r = 0; r < 4; ++r) {
      const int row  = wm + mt * 16 + quad * 4 + r;
      const int gpos = base + row;
      const int token = list[gpos];
      const float s = scale[(size_t)token * E + e];
#pragma unroll
      for (int nt = 0; nt < 2; ++nt) {
        const int j = jj + wn + nt * 16 + lm;
        const float g = accg[mt][nt][r] * s;
        const float u = accu[mt][nt][r] * s;
        const float hm = (g / (1.f + expf(-g))) * u;
        hmid_r[(size_t)gpos * IDIM + j] = f2bf(hm);
      }
    }
  }
}

// ---- routed down: dbuf[p,:] = hmid_r[p,:] . down_w[e]^T  (fp32 out) ----
// grid: x = out-col-tile (H/128 = 16, fastest), y = padded row-tile (early-exit)
__global__ __launch_bounds__(256) void down_routed_kernel(
    const unsigned short* __restrict__ hmid_r,
    const void* __restrict__ dwo_, const unsigned short* __restrict__ cdw,
    float* __restrict__ dbuf, const int* __restrict__ meta)
{
  if ((int)blockIdx.y >= meta[20]) return;
  const int bfmode = meta[0];
  const unsigned short* down_w = bfmode ? (const unsigned short*)dwo_ : cdw;

  __shared__ __attribute__((aligned(16))) unsigned short As[128 * 64];
  __shared__ __attribute__((aligned(16))) unsigned short Bs[128 * 64];

  const int tid = threadIdx.x;
  const int l = tid & 63, w = tid >> 6;
  const int e    = meta[64 + blockIdx.y];
  const int base = meta[136 + blockIdx.y];
  const int n0 = blockIdx.x * 128;

  const unsigned short* Bbase = down_w + ((size_t)e * H + n0) * IDIM;

  f32x4 acc[4][4] = {};
  const int wm = (w >> 1) * 64;
  const int wn = (w & 1) * 64;
  const int quad = l >> 4, lm = l & 15;

  for (int k0 = 0; k0 < IDIM; k0 += 64) {
#pragma unroll
    for (int j = 0; j < 4; ++j) {
      const int g = j * 256 + tid;
      const int r = g >> 3, c = g & 7;
      const int cc = c ^ (r & 7);
      gll16(hmid_r + (size_t)(base + r) * IDIM + k0 + cc * 8, &As[g * 8]);
    }
#pragma unroll
    for (int j = 0; j < 4; ++j) {
      const int g = j * 256 + tid;
      const int r = g >> 3, c = g & 7;
      const int cc = c ^ (r & 7);
      gll16(Bbase + (size_t)r * IDIM + k0 + cc * 8, &Bs[g * 8]);
    }
    __syncthreads();
#pragma unroll
    for (int ks = 0; ks < 64; ks += 32) {
      const int kc  = (ks >> 3) + quad;
      const int csw = (kc ^ (lm & 7)) * 8;
      bf16x8 a[4], b[4];
#pragma unroll
      for (int mt = 0; mt < 4; ++mt)
        a[mt] = *(const bf16x8*)&As[(wm + mt * 16 + lm) * 64 + csw];
#pragma unroll
      for (int nt = 0; nt < 4; ++nt)
        b[nt] = *(const bf16x8*)&Bs[(wn + nt * 16 + lm) * 64 + csw];
#pragma unroll
      for (int mt = 0; mt < 4; ++mt)
#pragma unroll
        for (int nt = 0; nt < 4; ++nt)
          acc[mt][nt] = __builtin_amdgcn_mfma_f32_16x16x32_bf16(a[mt], b[nt], acc[mt][nt], 0, 0, 0);
    }
    __syncthreads();
  }

#pragma unroll
  for (int mt = 0; mt < 4; ++mt)
#pragma unroll
    for (int nt = 0; nt < 4; ++nt)
#pragma unroll
      for (int r = 0; r < 4; ++r) {
        const int row = wm + mt * 16 + quad * 4 + r;
        const int n   = n0 + wn + nt * 16 + lm;
        dbuf[(size_t)(base + row) * H + n] = acc[mt][nt][r];
      }
}

// ---- shared down + gather-add of the 2 routed contributions ----
// grid: x = out-col-tile (16, fastest), y = token-tile (32)
__global__ __launch_bounds__(256) void down_shared_kernel(
    const unsigned short* __restrict__ hmid_sh,
    const void* __restrict__ sdwo_, const unsigned short* __restrict__ csdw,
    const float* __restrict__ dbuf, const int* __restrict__ tokpos,
    void* __restrict__ out, const int* __restrict__ meta)
{
  const int bfmode = meta[0];
  const unsigned short* sdown_w = bfmode ? (const unsigned short*)sdwo_ : csdw;

  __shared__ __attribute__((aligned(16))) unsigned short As[128 * 64];
  __shared__ __attribute__((aligned(16))) unsigned short Bs[128 * 64];

  const int tid = threadIdx.x;
  const int l = tid & 63, w = tid >> 6;
  const int m0 = blockIdx.y * 128;
  const int n0 = blockIdx.x * 128;

  f32x4 acc[4][4] = {};
  const int wm = (w >> 1) * 64;
  const int wn = (w & 1) * 64;
  const int quad = l >> 4, lm = l & 15;

  for (int k0 = 0; k0 < ISD; k0 += 64) {
#pragma unroll
    for (int j = 0; j < 4; ++j) {
      const int g = j * 256 + tid;
      const int r = g >> 3, c = g & 7;
      const int cc = c ^ (r & 7);
      gll16(hmid_sh + (size_t)(m0 + r) * ISD + k0 + cc * 8, &As[g * 8]);
    }
#pragma unroll
    for (int j = 0; j < 4; ++j) {
      const int g = j * 256 + tid;
      const int r = g >> 3, c = g & 7;
      const int cc = c ^ (r & 7);
      gll16(sdown_w + (size_t)(n0 + r) * ISD + k0 + cc * 8, &Bs[g * 8]);
    }
    __syncthreads();
#pragma unroll
    for (int ks = 0; ks < 64; ks += 32) {
      const int kc  = (ks >> 3) + quad;
      const int csw = (kc ^ (lm & 7)) * 8;
      bf16x8 a[4], b[4];
#pragma unroll
      for (int mt = 0; mt < 4; ++mt)
        a[mt] = *(const bf16x8*)&As[(wm + mt * 16 + lm) * 64 + csw];
#pragma unroll
      for (int nt = 0; nt < 4; ++nt)
        b[nt] = *(const bf16x8*)&Bs[(wn + nt * 16 + lm) * 64 + csw];
#pragma unroll
      for (int mt = 0; mt < 4; ++mt)
#pragma unroll
        for (int nt = 0; nt < 4; ++nt)
          acc[mt][nt] = __builtin_amdgcn_mfma_f32_16x16x32_bf16(a[mt], b[nt], acc[mt][nt], 0, 0, 0);
    }
    __syncthreads();
  }

  if (bfmode) {
    unsigned short* o = (unsigned short*)out;
#pragma unroll
    for (int mt = 0; mt < 4; ++mt)
#pragma unroll
      for (int r = 0; r < 4; ++r) {
        const int t = m0 + wm + mt * 16 + quad * 4 + r;
        const int p0 = tokpos[2 * t], p1 = tokpos[2 * t + 1];
#pragma unroll
        for (int nt = 0; nt < 4; ++nt) {
          const int n = n0 + wn + nt * 16 + lm;
          const float v = acc[mt][nt][r]
                        + dbuf[(size_t)p0 * H + n] + dbuf[(size_t)p1 * H + n];
          o[(size_t)t * H + n] = f2bf(v);
        }
      }
  } else {
    float* o = (float*)out;
#pragma unroll
    for (int mt = 0; mt < 4; ++mt)
#pragma unroll
      for (int r = 0; r < 4; ++r) {
        const int t = m0 + wm + mt * 16 + quad * 4 + r;
        const int p0 = tokpos[2 * t], p1 = tokpos[2 * t + 1];
#pragma unroll
        for (int nt = 0; nt < 4; ++nt) {
          const int n = n0 + wn + nt * 16 + lm;
          o[(size_t)t * H + n] = acc[mt][nt][r]
                               + dbuf[(size_t)p0 * H + n] + dbuf[(size_t)p1 * H + n];
        }
      }
  }
}

extern "C" void kernel_launch(void* const* d_in, const int* in_sizes, int n_in,
                              void* d_out, int out_size, void* d_ws, size_t ws_size,
                              hipStream_t stream) {
  const void* x   = d_in[0];
  const void* rw  = d_in[1];
  const void* gw  = d_in[2];
  const void* uw  = d_in[3];
  const void* dw  = d_in[4];
  const void* sgw = d_in[5];
  const void* suw = d_in[6];
  const void* sdw = d_in[7];

  char* wsb = (char*)d_ws;
  int*   meta   = (int*)wsb;                                  // 1024 B
  float* scale  = (float*)(wsb + 1024);                       // TOK*E fp32 (128 KiB)
  int*   topk   = (int*)(wsb + 1024 + (size_t)TOK * E * 4);   // TOK*2 (32 KiB)
  int*   list   = topk + (size_t)TOK * 2;                     // MAXROWS (36 KiB)
  int*   tokpos = list + MAXROWS;                             // TOK*2 (32 KiB)
  unsigned short* hmid_sh = (unsigned short*)(wsb + 234496);  // [TOK,ISD] bf16 (32 MiB)
  unsigned short* hmid_r  = hmid_sh + (size_t)TOK * ISD;      // [MAXROWS,IDIM] bf16 (18 MiB)
  unsigned short* cx   = hmid_r + (size_t)MAXROWS * IDIM;
  unsigned short* crw  = cx  + (size_t)TOK * H;
  unsigned short* cgw  = crw + (size_t)E * H;
  unsigned short* cuw  = cgw + (size_t)E * IDIM * H;
  unsigned short* cdw  = cuw + (size_t)E * IDIM * H;
  unsigned short* csgw = cdw + (size_t)E * H * IDIM;
  unsigned short* csuw = csgw + (size_t)ISD * H;
  unsigned short* csdw = csuw + (size_t)ISD * H;
  // routed-down fp32 buffer [MAXROWS,H] = 75.5 MB aliases cx..cuw (83.9 MB),
  // which are dead once the gate/up kernels complete; cdw/csdw are untouched.
  float* dbuf = (float*)cx;

  detect_kernel<<<1, 256, 0, stream>>>((const unsigned int*)x, meta);

  convert_kernel<<<1024, 256, 0, stream>>>((const float*)x,   cx,   (TOK * H) / 4,        meta);
  convert_kernel<<<16,   256, 0, stream>>>((const float*)rw,  crw,  (E * H) / 4,          meta);
  convert_kernel<<<1024, 256, 0, stream>>>((const float*)gw,  cgw,  (E * IDIM * H) / 4,   meta);
  convert_kernel<<<1024, 256, 0, stream>>>((const float*)uw,  cuw,  (E * IDIM * H) / 4,   meta);
  convert_kernel<<<1024, 256, 0, stream>>>((const float*)dw,  cdw,  (E * H * IDIM) / 4,   meta);
  convert_kernel<<<1024, 256, 0, stream>>>((const float*)sgw, csgw, (ISD * H) / 4,        meta);
  convert_kernel<<<1024, 256, 0, stream>>>((const float*)suw, csuw, (ISD * H) / 4,        meta);
  convert_kernel<<<1024, 256, 0, stream>>>((const float*)sdw, csdw, (ISD * H) / 4,        meta);

  router_kernel<<<TOK, 256, 0, stream>>>(x, rw, d_out, scale, meta, topk);
  scan_kernel<<<1, 256, 0, stream>>>(meta, list);
  scatter_kernel<<<TOK / 256, 256, 0, stream>>>(meta, topk, list, tokpos);

  dim3 g1(TOK / 128, ISD / 64);       // 32 x 64
  gateup_shared_kernel<<<g1, 256, 0, stream>>>(x, cx, sgw, csgw, suw, csuw, hmid_sh, meta);

  dim3 g2(MAXTILES, IDIM / 64);       // 72 x 16 (early-exit past nTiles)
  gateup_routed_kernel<<<g2, 256, 0, stream>>>(x, cx, gw, cgw, uw, cuw,
                                               scale, list, hmid_r, meta);

  dim3 g3(H / 128, MAXTILES);         // 16 x 72 (early-exit past nTiles)
  down_routed_kernel<<<g3, 256, 0, stream>>>(hmid_r, dw, cdw, dbuf, meta);

  dim3 g4(H / 128, TOK / 128);        // 16 x 32
  down_shared_kernel<<<g4, 256, 0, stream>>>(hmid_sh, sdw, csdw, dbuf, tokpos, d_out, meta);
}

// Round 2
// 898.719 us; speedup vs baseline: 1.2917x; 1.0407x over previous
//
#include <hip/hip_runtime.h>
#include <hip/hip_bf16.h>
#include <cstdint>
#include <cstddef>

typedef __bf16 bf16x8 __attribute__((ext_vector_type(8)));
typedef float  f32x4  __attribute__((ext_vector_type(4)));

static constexpr int TOK  = 4096;            // B*S
static constexpr int H    = 2048;
static constexpr int E    = 8;
static constexpr int IDIM = 1024;
static constexpr int ISD  = 4096;
static constexpr int MAXTILES = 72;          // >= max padded 128-row tiles (<=71)
static constexpr int MAXROWS  = MAXTILES * 128;  // 9216 >= 2*TOK + 8*127 padded

// meta layout (ints):
//  [0]      bf16-input flag
//  [4..11]  cnt[e]      (token count per expert)
//  [12..19] cursor[e]   (scatter cursors)
//  [20]     nTiles
//  [24..32] segStart[e] (padded prefix, segStart[8] = total padded rows)
//  [64..135]  tileExpert[t]
//  [136..207] tileBase[t]  (padded row offset of tile t)

// async global->LDS, 16B/lane; LDS dest = wave-uniform base + lane*16
__device__ __forceinline__ void gll16(const void* g, void* l) {
  __builtin_amdgcn_global_load_lds((const __attribute__((address_space(1))) void*)g,
                                   (__attribute__((address_space(3))) void*)l, 16, 0, 0);
}

__device__ __forceinline__ unsigned short f2bf(float f) {  // RNE fp32->bf16
  unsigned int u = __float_as_uint(f);
  u = (u + 0x7fffu + ((u >> 16) & 1u)) >> 16;
  return (unsigned short)u;
}

// ---- dtype detection + meta zeroing ----
__global__ __launch_bounds__(256) void detect_kernel(const unsigned int* __restrict__ x,
                                                     int* __restrict__ meta) {
  __shared__ int sh[256];
  const int tid = threadIdx.x;
  int c = 0;
  for (int i = tid; i < 1024; i += 256) {
    const unsigned int e = (x[i] >> 7) & 0xFFu;
    c += (e >= 100u && e <= 150u) ? 1 : 0;
  }
  sh[tid] = c;
  if (tid >= 4 && tid < 24) meta[tid] = 0;   // zero cnt[] and cursor[]
  __syncthreads();
  if (tid == 0) {
    int s = 0;
    for (int i = 0; i < 256; ++i) s += sh[i];
    meta[0] = (s > 512) ? 1 : 0;   // 1 => inputs bf16; 0 => fp32
  }
}

// ---- fused fp32 -> bf16 conversion for all 8 inputs (no-op when bf16) ----
__global__ __launch_bounds__(256) void convert_all_kernel(
    const float* __restrict__ s0, const float* __restrict__ s1,
    const float* __restrict__ s2, const float* __restrict__ s3,
    const float* __restrict__ s4, const float* __restrict__ s5,
    const float* __restrict__ s6, const float* __restrict__ s7,
    unsigned short* __restrict__ d0, unsigned short* __restrict__ d1,
    unsigned short* __restrict__ d2, unsigned short* __restrict__ d3,
    unsigned short* __restrict__ d4, unsigned short* __restrict__ d5,
    unsigned short* __restrict__ d6, unsigned short* __restrict__ d7,
    const int* __restrict__ flag)
{
  if (*flag) return;
  const int stride = gridDim.x * 256;
  const int base = blockIdx.x * 256 + threadIdx.x;
  auto go = [&](const float* s, unsigned short* d, int n4) {
    for (int i = base; i < n4; i += stride) {
      const float4 v = ((const float4*)s)[i];
      ushort4 o;
      o.x = f2bf(v.x); o.y = f2bf(v.y); o.z = f2bf(v.z); o.w = f2bf(v.w);
      ((ushort4*)d)[i] = o;
    }
  };
  go(s0, d0, (TOK * H) / 4);
  go(s1, d1, (E * H) / 4);
  go(s2, d2, (E * IDIM * H) / 4);
  go(s3, d3, (E * IDIM * H) / 4);
  go(s4, d4, (E * H * IDIM) / 4);
  go(s5, d5, (ISD * H) / 4);
  go(s6, d6, (ISD * H) / 4);
  go(s7, d7, (ISD * H) / 4);
}

// ---- router: fp32 logits, top-2, sigmoid, per-expert counting ----
__global__ __launch_bounds__(256) void router_kernel(
    const void* __restrict__ x_, const void* __restrict__ rw_,
    void* __restrict__ out, float* __restrict__ scale,
    int* __restrict__ meta, int* __restrict__ topk)
{
  const int bfmode = meta[0];
  const int t   = blockIdx.x;
  const int tid = threadIdx.x;
  const int l   = tid & 63, w = tid >> 6;
  const int off = tid * 8;

  float xs[8];
  if (bfmode) {
    bf16x8 v = *(const bf16x8*)((const unsigned short*)x_ + (size_t)t * H + off);
#pragma unroll
    for (int j = 0; j < 8; ++j) xs[j] = (float)v[j];
  } else {
    const float* xr = (const float*)x_ + (size_t)t * H + off;
    const float4 a = *(const float4*)xr;
    const float4 b = *(const float4*)(xr + 4);
    xs[0]=a.x; xs[1]=a.y; xs[2]=a.z; xs[3]=a.w; xs[4]=b.x; xs[5]=b.y; xs[6]=b.z; xs[7]=b.w;
  }

  float p[E];
#pragma unroll
  for (int e = 0; e < E; ++e) {
    float wv[8];
    if (bfmode) {
      bf16x8 v = *(const bf16x8*)((const unsigned short*)rw_ + (size_t)e * H + off);
#pragma unroll
      for (int j = 0; j < 8; ++j) wv[j] = (float)v[j];
    } else {
      const float* wr = (const float*)rw_ + (size_t)e * H + off;
      const float4 a = *(const float4*)wr;
      const float4 b = *(const float4*)(wr + 4);
      wv[0]=a.x; wv[1]=a.y; wv[2]=a.z; wv[3]=a.w; wv[4]=b.x; wv[5]=b.y; wv[6]=b.z; wv[7]=b.w;
    }
    float s = 0.f;
#pragma unroll
    for (int j = 0; j < 8; ++j) s = fmaf(xs[j], wv[j], s);
    p[e] = s;
  }
#pragma unroll
  for (int e = 0; e < E; ++e)
    for (int o = 32; o > 0; o >>= 1) p[e] += __shfl_down(p[e], o);

  __shared__ float red[E][4];
  __shared__ float lg[E];
  __shared__ float sres[2];
  __shared__ int   ires[2];
  if (l == 0) {
#pragma unroll
    for (int e = 0; e < E; ++e) red[e][w] = p[e];
  }
  __syncthreads();
  if (tid < E) {
    const float v = red[tid][0] + red[tid][1] + red[tid][2] + red[tid][3];
    lg[tid] = v;
    const size_t oi = (size_t)TOK * H + (size_t)t * E + tid;
    if (bfmode) ((unsigned short*)out)[oi] = f2bf(v);
    else        ((float*)out)[oi] = v;
  }
  __syncthreads();
  if (tid == 0) {
    int i0 = 0; float v0 = lg[0];
    for (int e = 1; e < E; ++e) if (lg[e] > v0) { v0 = lg[e]; i0 = e; }
    int i1 = -1; float v1 = 0.f; bool init = false;
    for (int e = 0; e < E; ++e) {
      if (e == i0) continue;
      if (!init || lg[e] > v1) { v1 = lg[e]; i1 = e; init = true; }
    }
    sres[0] = 1.f / (1.f + expf(-v0)); ires[0] = i0;
    sres[1] = 1.f / (1.f + expf(-v1)); ires[1] = i1;
    topk[2 * t + 0] = i0;
    topk[2 * t + 1] = i1;
    atomicAdd(&meta[4 + i0], 1);
    atomicAdd(&meta[4 + i1], 1);
  }
  __syncthreads();
  if (tid < E) {
    float s = 0.f;
    if (tid == ires[0]) s = sres[0];
    else if (tid == ires[1]) s = sres[1];
    scale[(size_t)t * E + tid] = s;
  }
}

// ---- tiny scan: padded segment starts + tile map; zero token list ----
__global__ __launch_bounds__(256) void scan_kernel(int* __restrict__ meta,
                                                   int* __restrict__ list) {
  const int tid = threadIdx.x;
  if (tid == 0) {
    int s = 0, nt = 0;
    for (int e = 0; e < E; ++e) {
      meta[24 + e] = s;
      const int cnt = meta[4 + e];
      const int tiles = (cnt + 127) >> 7;
      for (int i = 0; i < tiles; ++i) {
        meta[64 + nt]  = e;
        meta[136 + nt] = s + i * 128;
        ++nt;
      }
      s += tiles << 7;
    }
    meta[32] = s;    // total padded rows
    meta[20] = nt;   // total tiles
  }
  for (int i = tid; i < MAXROWS; i += 256) list[i] = 0;  // pad rows -> token 0
}

// ---- scatter token ids into per-expert padded lists ----
__global__ __launch_bounds__(256) void scatter_kernel(int* __restrict__ meta,
                                                      const int* __restrict__ topk,
                                                      int* __restrict__ list,
                                                      int* __restrict__ tokpos) {
  const int t = blockIdx.x * 256 + threadIdx.x;
  if (t >= TOK) return;
#pragma unroll
  for (int k = 0; k < 2; ++k) {
    const int e = topk[2 * t + k];
    const int p = atomicAdd(&meta[12 + e], 1);
    const int g = meta[24 + e] + p;
    list[g] = t;
    tokpos[2 * t + k] = g;
  }
}

// ============================================================================
// shared-expert gate+up: 8-phase 256-geometry pipeline (T2+T3+T4+T5).
// Tile: 256 tokens x 128 hmid cols; B-tile = 256 rows = [gate(128) | up(128)].
// 8 waves (wm 0..1 x wn 0..3), strip-interleaved:
//   wave wm owns m-strips {2*mt + wm}, mt 0..7  (mL = mt 0..3 -> Ah0, mH -> Ah1)
//   wave wn owns n-strips {wn + 4*nt}, nt 0..3  (nt 0,1 -> gate/Bh0; nt 2,3 -> up/Bh1)
// Strips s and s+8 share a wave -> gate/up pair in-register for the epilogue.
// Schedule per iteration (2 K-tiles, buf0 even / buf1 odd), stages (1 half/phase):
//   P1 (mL,nL) buf0  stage T1.Ah0     P5 (mL,nL) buf1  stage T2.Bh1
//   P2 (mL,nH) buf0  stage T1.Bh0     P6 (mL,nH) buf1  stage T2.Ah1
//   P3 (mH,nH) buf0  stage T2.Ah0     P7 (mH,nH) buf1  stage T3.Bh1
//   P4 (mH,nL) buf0  stage T2.Bh0     P8 (mH,nL) buf1  stage T3.Ah1
//   vmcnt(4) at P4/P8 (2 half-tiles in flight); never 0 except peeled last iter.
// Slot-overwrite and landing guarantees verified half-by-half (see derivation).
// ============================================================================
#define GU_BAR_   __builtin_amdgcn_s_barrier()
#define GU_LGKM0_ { asm volatile("s_waitcnt lgkmcnt(0)" ::: "memory"); \
                    __builtin_amdgcn_sched_barrier(0); }
#define GU_VM4_   asm volatile("s_waitcnt vmcnt(4)" ::: "memory")
#define GU_VM0_   asm volatile("s_waitcnt vmcnt(0)" ::: "memory")

#define LDA_(p, mh) { _Pragma("unroll") for (int q2 = 0; q2 < 4; ++q2) { \
  _Pragma("unroll") for (int ks = 0; ks < 2; ++ks) { \
    const int row_ = 32 * (4 * (mh) + q2) + 16 * wm + lm; \
    a[q2][ks] = *(const bf16x8*)&ldsA[(p) * 16384 + row_ * 64 + \
                                      (((ks * 4 + quad) ^ (lm & 7)) * 8)]; } } }

#define LDB_(p, nh) { _Pragma("unroll") for (int nt2 = 0; nt2 < 2; ++nt2) { \
  _Pragma("unroll") for (int ks = 0; ks < 2; ++ks) { \
    const int row_ = 16 * (wn + 4 * (2 * (nh) + nt2)) + lm; \
    bb[nh][nt2][ks] = *(const bf16x8*)&ldsB[(p) * 16384 + row_ * 64 + \
                                            (((ks * 4 + quad) ^ (lm & 7)) * 8)]; } } }

#define MFMA_(mh, nh) { __builtin_amdgcn_s_setprio(1); \
  _Pragma("unroll") for (int q2 = 0; q2 < 4; ++q2) \
  _Pragma("unroll") for (int nt2 = 0; nt2 < 2; ++nt2) \
  _Pragma("unroll") for (int ks = 0; ks < 2; ++ks) \
    acc[4 * (mh) + q2][2 * (nh) + nt2] = __builtin_amdgcn_mfma_f32_16x16x32_bf16( \
      a[q2][ks], bb[nh][nt2][ks], acc[4 * (mh) + q2][2 * (nh) + nt2], 0, 0, 0); \
  __builtin_amdgcn_s_setprio(0); }

__global__ __launch_bounds__(512, 2) void gateup_shared_kernel(
    const void* __restrict__ xo_,  const unsigned short* __restrict__ cx,
    const void* __restrict__ sgo_, const unsigned short* __restrict__ csgw,
    const void* __restrict__ suo_, const unsigned short* __restrict__ csuw,
    unsigned short* __restrict__ hmid_sh, const int* __restrict__ meta)
{
  extern __shared__ unsigned short lds[];
  unsigned short* ldsA = lds;             // [2][256*64] bf16 (64 KiB)
  unsigned short* ldsB = lds + 32768;     // [2][256*64] bf16 (64 KiB)

  const int bfmode = meta[0];
  const unsigned short* x  = bfmode ? (const unsigned short*)xo_  : cx;
  const unsigned short* gw = bfmode ? (const unsigned short*)sgo_ : csgw;
  const unsigned short* uw = bfmode ? (const unsigned short*)suo_ : csuw;

  const int tid = threadIdx.x;
  const int l = tid & 63, w = tid >> 6;
  const int wm = w >> 2, wn = w & 3;
  const int quad = l >> 4, lm = l & 15;
  const int m0 = blockIdx.x * 256;
  const int jb = blockIdx.y * 128;

  const unsigned short* gB = gw + (size_t)jb * H;
  const unsigned short* uB = uw + (size_t)jb * H;

  // staging: half-tile = 128 rows x 64 cols; 2 gll16 per thread; XOR-swizzled src
  const int sr0 = tid >> 3,         sc0 = tid & 7;
  const int sr1 = (tid + 512) >> 3, sc1 = (tid + 512) & 7;
  const int scc0 = sc0 ^ (sr0 & 7), scc1 = sc1 ^ (sr1 & 7);
  const int sd0 = tid * 8, sd1 = (tid + 512) * 8;   // LDS dst (shorts), linear

  auto stA = [&](int kt, int half) {
    unsigned short* d = ldsA + (kt & 1) * 16384 + half * 8192;
    const unsigned short* s = x + (size_t)(m0 + half * 128) * H + kt * 64;
    gll16(s + (size_t)sr0 * H + scc0 * 8, d + sd0);
    gll16(s + (size_t)sr1 * H + scc1 * 8, d + sd1);
  };
  auto stB = [&](int kt, int half) {
    unsigned short* d = ldsB + (kt & 1) * 16384 + half * 8192;
    const unsigned short* s = (half ? uB : gB) + kt * 64;
    gll16(s + (size_t)sr0 * H + scc0 * 8, d + sd0);
    gll16(s + (size_t)sr1 * H + scc1 * 8, d + sd1);
  };

  f32x4 acc[8][4] = {};
  bf16x8 a[4][2];
  bf16x8 bb[2][2][2];

  // prologue: T0 complete + T1.{Bh1,Ah1} issued (mimics steady-state P7,P8)
  stA(0, 0); stB(0, 0); stB(0, 1); stA(0, 1);
  stB(1, 1); stA(1, 1);
  GU_VM4_; GU_BAR_;

  for (int i = 0; i < (H / 128) - 1; ++i) {
    const int t0 = 2 * i, t1 = 2 * i + 1;
    // P1: (mL,nL) buf0
    LDA_(0, 0); LDB_(0, 0); stA(t1, 0);
    GU_BAR_; GU_LGKM0_; MFMA_(0, 0); GU_BAR_;
    // P2: (mL,nH) buf0
    LDB_(0, 1); stB(t1, 0);
    GU_BAR_; GU_LGKM0_; MFMA_(0, 1); GU_BAR_;
    // P3: (mH,nH) buf0
    LDA_(0, 1); stA(t0 + 2, 0);
    GU_BAR_; GU_LGKM0_; MFMA_(1, 1); GU_BAR_;
    // P4: (mH,nL) buf0 (bb[0] persists from P1)
    stB(t0 + 2, 0); GU_VM4_;
    GU_BAR_; GU_LGKM0_; MFMA_(1, 0); GU_BAR_;
    // P5: (mL,nL) buf1
    LDA_(1, 0); LDB_(1, 0); stB(t0 + 2, 1);
    GU_BAR_; GU_LGKM0_; MFMA_(0, 0); GU_BAR_;
    // P6: (mL,nH) buf1
    LDB_(1, 1); stA(t0 + 2, 1);
    GU_BAR_; GU_LGKM0_; MFMA_(0, 1); GU_BAR_;
    // P7: (mH,nH) buf1
    LDA_(1, 1); stB(t1 + 2, 1);
    GU_BAR_; GU_LGKM0_; MFMA_(1, 1); GU_BAR_;
    // P8: (mH,nL) buf1 (bb[0] persists from P5)
    stA(t1 + 2, 1); GU_VM4_;
    GU_BAR_; GU_LGKM0_; MFMA_(1, 0); GU_BAR_;
  }

  // peeled last iteration (T = H/64-2, H/64-1): no lookahead staging, vmcnt(0)
  {
    const int t1 = H / 64 - 1;
    LDA_(0, 0); LDB_(0, 0); stA(t1, 0);
    GU_BAR_; GU_LGKM0_; MFMA_(0, 0); GU_BAR_;
    LDB_(0, 1); stB(t1, 0);
    GU_BAR_; GU_LGKM0_; MFMA_(0, 1); GU_BAR_;
    LDA_(0, 1);
    GU_BAR_; GU_LGKM0_; MFMA_(1, 1); GU_BAR_;
    GU_VM0_;
    GU_BAR_; GU_LGKM0_; MFMA_(1, 0); GU_BAR_;
    LDA_(1, 0); LDB_(1, 0);
    GU_BAR_; GU_LGKM0_; MFMA_(0, 0); GU_BAR_;
    LDB_(1, 1);
    GU_BAR_; GU_LGKM0_; MFMA_(0, 1); GU_BAR_;
    LDA_(1, 1);
    GU_BAR_; GU_LGKM0_; MFMA_(1, 1); GU_BAR_;
    MFMA_(1, 0);
  }

  // epilogue: gate (nt 0,1) pairs with up (nt 2,3) in-wave, in-register
#pragma unroll
  for (int mt = 0; mt < 8; ++mt) {
    const int trow = m0 + 32 * mt + 16 * wm + quad * 4;
#pragma unroll
    for (int ntp = 0; ntp < 2; ++ntp) {
      const int col = jb + wn * 16 + ntp * 64 + lm;
#pragma unroll
      for (int rr = 0; rr < 4; ++rr) {
        const float g = acc[mt][ntp][rr];
        const float u = acc[mt][ntp + 2][rr];
        const float hm = (g / (1.f + expf(-g))) * u;
        hmid_sh[(size_t)(trow + rr) * ISD + col] = f2bf(hm);
      }
    }
  }
}

// ---- routed gate+up over gathered token lists (top-2 sparsity) ----
// grid: x = padded row-tile (MAXTILES, early-exit), y = col-tile (IDIM/64 = 16)
__global__ __launch_bounds__(256) void gateup_routed_kernel(
    const void* __restrict__ xo_,  const unsigned short* __restrict__ cx,
    const void* __restrict__ gwo_, const unsigned short* __restrict__ cgw,
    const void* __restrict__ uwo_, const unsigned short* __restrict__ cuw,
    const float* __restrict__ scale, const int* __restrict__ list,
    unsigned short* __restrict__ hmid_r, const int* __restrict__ meta)
{
  if ((int)blockIdx.x >= meta[20]) return;
  const int bfmode = meta[0];
  const unsigned short* x      = bfmode ? (const unsigned short*)xo_  : cx;
  const unsigned short* gate_w = bfmode ? (const unsigned short*)gwo_ : cgw;
  const unsigned short* up_w   = bfmode ? (const unsigned short*)uwo_ : cuw;

  __shared__ __attribute__((aligned(16))) unsigned short As[128 * 64];
  __shared__ __attribute__((aligned(16))) unsigned short Bgs[64 * 64];
  __shared__ __attribute__((aligned(16))) unsigned short Bus[64 * 64];

  const int tid = threadIdx.x;
  const int l = tid & 63, w = tid >> 6;
  const int e    = meta[64 + blockIdx.x];
  const int base = meta[136 + blockIdx.x];
  const int jj   = blockIdx.y * 64;

  const unsigned short* gB = gate_w + ((size_t)e * IDIM + jj) * H;
  const unsigned short* uB = up_w   + ((size_t)e * IDIM + jj) * H;

  // gathered A-row tokens for this thread's 4 staging loads (reused every k0)
  int tok[4];
#pragma unroll
  for (int j = 0; j < 4; ++j) tok[j] = list[base + ((j * 256 + tid) >> 3)];

  f32x4 accg[4][2] = {};
  f32x4 accu[4][2] = {};
  const int wm = (w >> 1) * 64;
  const int wn = (w & 1) * 32;
  const int quad = l >> 4, lm = l & 15;

  for (int k0 = 0; k0 < H; k0 += 64) {
#pragma unroll
    for (int j = 0; j < 4; ++j) {
      const int g = j * 256 + tid;
      const int r = g >> 3, c = g & 7;
      const int cc = c ^ (r & 7);
      gll16(x + (size_t)tok[j] * H + k0 + cc * 8, &As[g * 8]);
    }
#pragma unroll
    for (int j = 0; j < 2; ++j) {
      const int g = j * 256 + tid;
      const int r = g >> 3, c = g & 7;
      const int cc = c ^ (r & 7);
      gll16(gB + (size_t)r * H + k0 + cc * 8, &Bgs[g * 8]);
      gll16(uB + (size_t)r * H + k0 + cc * 8, &Bus[g * 8]);
    }
    __syncthreads();
#pragma unroll
    for (int ks = 0; ks < 64; ks += 32) {
      const int kc  = (ks >> 3) + quad;
      const int csw = (kc ^ (lm & 7)) * 8;
      bf16x8 a[4], bg[2], bu[2];
#pragma unroll
      for (int mt = 0; mt < 4; ++mt)
        a[mt] = *(const bf16x8*)&As[(wm + mt * 16 + lm) * 64 + csw];
#pragma unroll
      for (int nt = 0; nt < 2; ++nt) {
        bg[nt] = *(const bf16x8*)&Bgs[(wn + nt * 16 + lm) * 64 + csw];
        bu[nt] = *(const bf16x8*)&Bus[(wn + nt * 16 + lm) * 64 + csw];
      }
#pragma unroll
      for (int mt = 0; mt < 4; ++mt)
#pragma unroll
        for (int nt = 0; nt < 2; ++nt) {
          accg[mt][nt] = __builtin_amdgcn_mfma_f32_16x16x32_bf16(a[mt], bg[nt], accg[mt][nt], 0, 0, 0);
          accu[mt][nt] = __builtin_amdgcn_mfma_f32_16x16x32_bf16(a[mt], bu[nt], accu[mt][nt], 0, 0, 0);
        }
    }
    __syncthreads();
  }

#pragma unroll
  for (int mt = 0; mt < 4; ++mt) {
#pragma unroll
    for (int r = 0; r < 4; ++r) {
      const int row  = wm + mt * 16 + quad * 4 + r;
      const int gpos = base + row;
      const int token = list[gpos];
      const float s = scale[(size_t)token * E + e];
#pragma unroll
      for (int nt = 0; nt < 2; ++nt) {
        const int j = jj + wn + nt * 16 + lm;
        const float g = accg[mt][nt][r] * s;
        const float u = accu[mt][nt][r] * s;
        const float hm = (g / (1.f + expf(-g))) * u;
        hmid_r[(size_t)gpos * IDIM + j] = f2bf(hm);
      }
    }
  }
}

// ---- routed down: dbuf[p,:] = hmid_r[p,:] . down_w[e]^T  (fp32 out) ----
// grid: x = out-col-tile (H/128 = 16, fastest), y = padded row-tile (early-exit)
__global__ __launch_bounds__(256) void down_routed_kernel(
    const unsigned short* __restrict__ hmid_r,
    const void* __restrict__ dwo_, const unsigned short* __restrict__ cdw,
    float* __restrict__ dbuf, const int* __restrict__ meta)
{
  if ((int)blockIdx.y >= meta[20]) return;
  const int bfmode = meta[0];
  const unsigned short* down_w = bfmode ? (const unsigned short*)dwo_ : cdw;

  __shared__ __attribute__((aligned(16))) unsigned short As[128 * 64];
  __shared__ __attribute__((aligned(16))) unsigned short Bs[128 * 64];

  const int tid = threadIdx.x;
  const int l = tid & 63, w = tid >> 6;
  const int e    = meta[64 + blockIdx.y];
  const int base = meta[136 + blockIdx.y];
  const int n0 = blockIdx.x * 128;

  const unsigned short* Bbase = down_w + ((size_t)e * H + n0) * IDIM;

  f32x4 acc[4][4] = {};
  const int wm = (w >> 1) * 64;
  const int wn = (w & 1) * 64;
  const int quad = l >> 4, lm = l & 15;

  for (int k0 = 0; k0 < IDIM; k0 += 64) {
#pragma unroll
    for (int j = 0; j < 4; ++j) {
      const int g = j * 256 + tid;
      const int r = g >> 3, c = g & 7;
      const int cc = c ^ (r & 7);
      gll16(hmid_r + (size_t)(base + r) * IDIM + k0 + cc * 8, &As[g * 8]);
    }
#pragma unroll
    for (int j = 0; j < 4; ++j) {
      const int g = j * 256 + tid;
      const int r = g >> 3, c = g & 7;
      const int cc = c ^ (r & 7);
      gll16(Bbase + (size_t)r * IDIM + k0 + cc * 8, &Bs[g * 8]);
    }
    __syncthreads();
#pragma unroll
    for (int ks = 0; ks < 64; ks += 32) {
      const int kc  = (ks >> 3) + quad;
      const int csw = (kc ^ (lm & 7)) * 8;
      bf16x8 a[4], b[4];
#pragma unroll
      for (int mt = 0; mt < 4; ++mt)
        a[mt] = *(const bf16x8*)&As[(wm + mt * 16 + lm) * 64 + csw];
#pragma unroll
      for (int nt = 0; nt < 4; ++nt)
        b[nt] = *(const bf16x8*)&Bs[(wn + nt * 16 + lm) * 64 + csw];
#pragma unroll
      for (int mt = 0; mt < 4; ++mt)
#pragma unroll
        for (int nt = 0; nt < 4; ++nt)
          acc[mt][nt] = __builtin_amdgcn_mfma_f32_16x16x32_bf16(a[mt], b[nt], acc[mt][nt], 0, 0, 0);
    }
    __syncthreads();
  }

#pragma unroll
  for (int mt = 0; mt < 4; ++mt)
#pragma unroll
    for (int nt = 0; nt < 4; ++nt)
#pragma unroll
      for (int r = 0; r < 4; ++r) {
        const int row = wm + mt * 16 + quad * 4 + r;
        const int n   = n0 + wn + nt * 16 + lm;
        dbuf[(size_t)(base + row) * H + n] = acc[mt][nt][r];
      }
}

// ---- shared down + gather-add of the 2 routed contributions ----
// grid: x = out-col-tile (16, fastest), y = token-tile (32)
__global__ __launch_bounds__(256) void down_shared_kernel(
    const unsigned short* __restrict__ hmid_sh,
    const void* __restrict__ sdwo_, const unsigned short* __restrict__ csdw,
    const float* __restrict__ dbuf, const int* __restrict__ tokpos,
    void* __restrict__ out, const int* __restrict__ meta)
{
  const int bfmode = meta[0];
  const unsigned short* sdown_w = bfmode ? (const unsigned short*)sdwo_ : csdw;

  __shared__ __attribute__((aligned(16))) unsigned short As[128 * 64];
  __shared__ __attribute__((aligned(16))) unsigned short Bs[128 * 64];

  const int tid = threadIdx.x;
  const int l = tid & 63, w = tid >> 6;
  const int m0 = blockIdx.y * 128;
  const int n0 = blockIdx.x * 128;

  f32x4 acc[4][4] = {};
  const int wm = (w >> 1) * 64;
  const int wn = (w & 1) * 64;
  const int quad = l >> 4, lm = l & 15;

  for (int k0 = 0; k0 < ISD; k0 += 64) {
#pragma unroll
    for (int j = 0; j < 4; ++j) {
      const int g = j * 256 + tid;
      const int r = g >> 3, c = g & 7;
      const int cc = c ^ (r & 7);
      gll16(hmid_sh + (size_t)(m0 + r) * ISD + k0 + cc * 8, &As[g * 8]);
    }
#pragma unroll
    for (int j = 0; j < 4; ++j) {
      const int g = j * 256 + tid;
      const int r = g >> 3, c = g & 7;
      const int cc = c ^ (r & 7);
      gll16(sdown_w + (size_t)(n0 + r) * ISD + k0 + cc * 8, &Bs[g * 8]);
    }
    __syncthreads();
#pragma unroll
    for (int ks = 0; ks < 64; ks += 32) {
      const int kc  = (ks >> 3) + quad;
      const int csw = (kc ^ (lm & 7)) * 8;
      bf16x8 a[4], b[4];
#pragma unroll
      for (int mt = 0; mt < 4; ++mt)
        a[mt] = *(const bf16x8*)&As[(wm + mt * 16 + lm) * 64 + csw];
#pragma unroll
      for (int nt = 0; nt < 4; ++nt)
        b[nt] = *(const bf16x8*)&Bs[(wn + nt * 16 + lm) * 64 + csw];
#pragma unroll
      for (int mt = 0; mt < 4; ++mt)
#pragma unroll
        for (int nt = 0; nt < 4; ++nt)
          acc[mt][nt] = __builtin_amdgcn_mfma_f32_16x16x32_bf16(a[mt], b[nt], acc[mt][nt], 0, 0, 0);
    }
    __syncthreads();
  }

  if (bfmode) {
    unsigned short* o = (unsigned short*)out;
#pragma unroll
    for (int mt = 0; mt < 4; ++mt)
#pragma unroll
      for (int r = 0; r < 4; ++r) {
        const int t = m0 + wm + mt * 16 + quad * 4 + r;
        const int p0 = tokpos[2 * t], p1 = tokpos[2 * t + 1];
#pragma unroll
        for (int nt = 0; nt < 4; ++nt) {
          const int n = n0 + wn + nt * 16 + lm;
          const float v = acc[mt][nt][r]
                        + dbuf[(size_t)p0 * H + n] + dbuf[(size_t)p1 * H + n];
          o[(size_t)t * H + n] = f2bf(v);
        }
      }
  } else {
    float* o = (float*)out;
#pragma unroll
    for (int mt = 0; mt < 4; ++mt)
#pragma unroll
      for (int r = 0; r < 4; ++r) {
        const int t = m0 + wm + mt * 16 + quad * 4 + r;
        const int p0 = tokpos[2 * t], p1 = tokpos[2 * t + 1];
#pragma unroll
        for (int nt = 0; nt < 4; ++nt) {
          const int n = n0 + wn + nt * 16 + lm;
          o[(size_t)t * H + n] = acc[mt][nt][r]
                               + dbuf[(size_t)p0 * H + n] + dbuf[(size_t)p1 * H + n];
        }
      }
  }
}

extern "C" void kernel_launch(void* const* d_in, const int* in_sizes, int n_in,
                              void* d_out, int out_size, void* d_ws, size_t ws_size,
                              hipStream_t stream) {
  const void* x   = d_in[0];
  const void* rw  = d_in[1];
  const void* gw  = d_in[2];
  const void* uw  = d_in[3];
  const void* dw  = d_in[4];
  const void* sgw = d_in[5];
  const void* suw = d_in[6];
  const void* sdw = d_in[7];

  char* wsb = (char*)d_ws;
  int*   meta   = (int*)wsb;                                  // 1024 B
  float* scale  = (float*)(wsb + 1024);                       // TOK*E fp32 (128 KiB)
  int*   topk   = (int*)(wsb + 1024 + (size_t)TOK * E * 4);   // TOK*2 (32 KiB)
  int*   list   = topk + (size_t)TOK * 2;                     // MAXROWS (36 KiB)
  int*   tokpos = list + MAXROWS;                             // TOK*2 (32 KiB)
  unsigned short* hmid_sh = (unsigned short*)(wsb + 234496);  // [TOK,ISD] bf16 (32 MiB)
  unsigned short* hmid_r  = hmid_sh + (size_t)TOK * ISD;      // [MAXROWS,IDIM] bf16 (18 MiB)
  unsigned short* cx   = hmid_r + (size_t)MAXROWS * IDIM;
  unsigned short* crw  = cx  + (size_t)TOK * H;
  unsigned short* cgw  = crw + (size_t)E * H;
  unsigned short* cuw  = cgw + (size_t)E * IDIM * H;
  unsigned short* cdw  = cuw + (size_t)E * IDIM * H;
  unsigned short* csgw = cdw + (size_t)E * H * IDIM;
  unsigned short* csuw = csgw + (size_t)ISD * H;
  unsigned short* csdw = csuw + (size_t)ISD * H;
  // routed-down fp32 buffer [MAXROWS,H] = 75.5 MB aliases cx..cuw (83.9 MB),
  // which are dead once the gate/up kernels complete; cdw/csdw are untouched.
  float* dbuf = (float*)cx;

  static int attr_set = 0;
  if (!attr_set) {
    hipFuncSetAttribute(reinterpret_cast<const void*>(gateup_shared_kernel),
                        hipFuncAttributeMaxDynamicSharedMemorySize, 131072);
    attr_set = 1;
  }

  detect_kernel<<<1, 256, 0, stream>>>((const unsigned int*)x, meta);

  convert_all_kernel<<<2048, 256, 0, stream>>>(
      (const float*)x, (const float*)rw, (const float*)gw, (const float*)uw,
      (const float*)dw, (const float*)sgw, (const float*)suw, (const float*)sdw,
      cx, crw, cgw, cuw, cdw, csgw, csuw, csdw, meta);

  router_kernel<<<TOK, 256, 0, stream>>>(x, rw, d_out, scale, meta, topk);
  scan_kernel<<<1, 256, 0, stream>>>(meta, list);
  scatter_kernel<<<TOK / 256, 256, 0, stream>>>(meta, topk, list, tokpos);

  dim3 g1(TOK / 256, ISD / 128);      // 16 x 32, 512 threads, 128 KiB dynamic LDS
  gateup_shared_kernel<<<g1, 512, 131072, stream>>>(x, cx, sgw, csgw, suw, csuw,
                                                    hmid_sh, meta);

  dim3 g2(MAXTILES, IDIM / 64);       // 72 x 16 (early-exit past nTiles)
  gateup_routed_kernel<<<g2, 256, 0, stream>>>(x, cx, gw, cgw, uw, cuw,
                                               scale, list, hmid_r, meta);

  dim3 g3(H / 128, MAXTILES);         // 16 x 72 (early-exit past nTiles)
  down_routed_kernel<<<g3, 256, 0, stream>>>(hmid_r, dw, cdw, dbuf, meta);

  dim3 g4(H / 128, TOK / 128);        // 16 x 32
  down_shared_kernel<<<g4, 256, 0, stream>>>(hmid_sh, sdw, csdw, dbuf, tokpos, d_out, meta);
}

// Round 3
// 865.921 us; speedup vs baseline: 1.3406x; 1.0379x over previous
//
#include <hip/hip_runtime.h>
#include <hip/hip_bf16.h>
#include <cstdint>
#include <cstddef>

typedef __bf16 bf16x8 __attribute__((ext_vector_type(8)));
typedef float  f32x4  __attribute__((ext_vector_type(4)));

static constexpr int TOK  = 4096;            // B*S
static constexpr int H    = 2048;
static constexpr int E    = 8;
static constexpr int IDIM = 1024;
static constexpr int ISD  = 4096;
static constexpr int MAXT256 = 40;           // max 256-row tiles (32 + 8 remainders)
static constexpr int MAXT128 = 80;           // = 2 * MAXT256
static constexpr int MAXROWS = MAXT256 * 256;  // 10240 >= 2*TOK + 8*255 padded

// meta layout (ints):
//  [0]       bf16-input flag
//  [4..11]   cnt[e]       (token count per expert)
//  [12..19]  cursor[e]    (scatter cursors)
//  [20]      nTiles256    [21] nTiles128
//  [24..31]  segStart[e]  (256-padded prefix)   [32] total padded rows
//  [64..103]   tileExpert256[t]   [104..143] tileBase256[t]
//  [144..223]  tileExpert128[t]   [224..303] tileBase128[t]

// async global->LDS, 16B/lane; LDS dest = wave-uniform base + lane*16
__device__ __forceinline__ void gll16(const void* g, void* l) {
  __builtin_amdgcn_global_load_lds((const __attribute__((address_space(1))) void*)g,
                                   (__attribute__((address_space(3))) void*)l, 16, 0, 0);
}

__device__ __forceinline__ unsigned short f2bf(float f) {  // RNE fp32->bf16
  unsigned int u = __float_as_uint(f);
  u = (u + 0x7fffu + ((u >> 16) & 1u)) >> 16;
  return (unsigned short)u;
}

// ---- dtype detection + meta zeroing ----
__global__ __launch_bounds__(256) void detect_kernel(const unsigned int* __restrict__ x,
                                                     int* __restrict__ meta) {
  __shared__ int sh[256];
  const int tid = threadIdx.x;
  int c = 0;
  for (int i = tid; i < 1024; i += 256) {
    const unsigned int e = (x[i] >> 7) & 0xFFu;
    c += (e >= 100u && e <= 150u) ? 1 : 0;
  }
  sh[tid] = c;
  if (tid >= 4 && tid < 24) meta[tid] = 0;   // zero cnt[] and cursor[]
  __syncthreads();
  if (tid == 0) {
    int s = 0;
    for (int i = 0; i < 256; ++i) s += sh[i];
    meta[0] = (s > 512) ? 1 : 0;   // 1 => inputs bf16; 0 => fp32
  }
}

// ---- fused fp32 -> bf16 conversion for all 8 inputs (no-op when bf16) ----
__global__ __launch_bounds__(256) void convert_all_kernel(
    const float* __restrict__ s0, const float* __restrict__ s1,
    const float* __restrict__ s2, const float* __restrict__ s3,
    const float* __restrict__ s4, const float* __restrict__ s5,
    const float* __restrict__ s6, const float* __restrict__ s7,
    unsigned short* __restrict__ d0, unsigned short* __restrict__ d1,
    unsigned short* __restrict__ d2, unsigned short* __restrict__ d3,
    unsigned short* __restrict__ d4, unsigned short* __restrict__ d5,
    unsigned short* __restrict__ d6, unsigned short* __restrict__ d7,
    const int* __restrict__ flag)
{
  if (*flag) return;
  const int stride = gridDim.x * 256;
  const int base = blockIdx.x * 256 + threadIdx.x;
  auto go = [&](const float* s, unsigned short* d, int n4) {
    for (int i = base; i < n4; i += stride) {
      const float4 v = ((const float4*)s)[i];
      ushort4 o;
      o.x = f2bf(v.x); o.y = f2bf(v.y); o.z = f2bf(v.z); o.w = f2bf(v.w);
      ((ushort4*)d)[i] = o;
    }
  };
  go(s0, d0, (TOK * H) / 4);
  go(s1, d1, (E * H) / 4);
  go(s2, d2, (E * IDIM * H) / 4);
  go(s3, d3, (E * IDIM * H) / 4);
  go(s4, d4, (E * H * IDIM) / 4);
  go(s5, d5, (ISD * H) / 4);
  go(s6, d6, (ISD * H) / 4);
  go(s7, d7, (ISD * H) / 4);
}

// ---- router: fp32 logits, top-2, sigmoid, per-expert counting ----
__global__ __launch_bounds__(256) void router_kernel(
    const void* __restrict__ x_, const void* __restrict__ rw_,
    void* __restrict__ out, float* __restrict__ scale,
    int* __restrict__ meta, int* __restrict__ topk)
{
  const int bfmode = meta[0];
  const int t   = blockIdx.x;
  const int tid = threadIdx.x;
  const int l   = tid & 63, w = tid >> 6;
  const int off = tid * 8;

  float xs[8];
  if (bfmode) {
    bf16x8 v = *(const bf16x8*)((const unsigned short*)x_ + (size_t)t * H + off);
#pragma unroll
    for (int j = 0; j < 8; ++j) xs[j] = (float)v[j];
  } else {
    const float* xr = (const float*)x_ + (size_t)t * H + off;
    const float4 a = *(const float4*)xr;
    const float4 b = *(const float4*)(xr + 4);
    xs[0]=a.x; xs[1]=a.y; xs[2]=a.z; xs[3]=a.w; xs[4]=b.x; xs[5]=b.y; xs[6]=b.z; xs[7]=b.w;
  }

  float p[E];
#pragma unroll
  for (int e = 0; e < E; ++e) {
    float wv[8];
    if (bfmode) {
      bf16x8 v = *(const bf16x8*)((const unsigned short*)rw_ + (size_t)e * H + off);
#pragma unroll
      for (int j = 0; j < 8; ++j) wv[j] = (float)v[j];
    } else {
      const float* wr = (const float*)rw_ + (size_t)e * H + off;
      const float4 a = *(const float4*)wr;
      const float4 b = *(const float4*)(wr + 4);
      wv[0]=a.x; wv[1]=a.y; wv[2]=a.z; wv[3]=a.w; wv[4]=b.x; wv[5]=b.y; wv[6]=b.z; wv[7]=b.w;
    }
    float s = 0.f;
#pragma unroll
    for (int j = 0; j < 8; ++j) s = fmaf(xs[j], wv[j], s);
    p[e] = s;
  }
#pragma unroll
  for (int e = 0; e < E; ++e)
    for (int o = 32; o > 0; o >>= 1) p[e] += __shfl_down(p[e], o);

  __shared__ float red[E][4];
  __shared__ float lg[E];
  __shared__ float sres[2];
  __shared__ int   ires[2];
  if (l == 0) {
#pragma unroll
    for (int e = 0; e < E; ++e) red[e][w] = p[e];
  }
  __syncthreads();
  if (tid < E) {
    const float v = red[tid][0] + red[tid][1] + red[tid][2] + red[tid][3];
    lg[tid] = v;
    const size_t oi = (size_t)TOK * H + (size_t)t * E + tid;
    if (bfmode) ((unsigned short*)out)[oi] = f2bf(v);
    else        ((float*)out)[oi] = v;
  }
  __syncthreads();
  if (tid == 0) {
    int i0 = 0; float v0 = lg[0];
    for (int e = 1; e < E; ++e) if (lg[e] > v0) { v0 = lg[e]; i0 = e; }
    int i1 = -1; float v1 = 0.f; bool init = false;
    for (int e = 0; e < E; ++e) {
      if (e == i0) continue;
      if (!init || lg[e] > v1) { v1 = lg[e]; i1 = e; init = true; }
    }
    sres[0] = 1.f / (1.f + expf(-v0)); ires[0] = i0;
    sres[1] = 1.f / (1.f + expf(-v1)); ires[1] = i1;
    topk[2 * t + 0] = i0;
    topk[2 * t + 1] = i1;
    atomicAdd(&meta[4 + i0], 1);
    atomicAdd(&meta[4 + i1], 1);
  }
  __syncthreads();
  if (tid < E) {
    float s = 0.f;
    if (tid == ires[0]) s = sres[0];
    else if (tid == ires[1]) s = sres[1];
    scale[(size_t)t * E + tid] = s;
  }
}

// ---- tiny scan: 256-padded segment starts + both tile maps; zero token list ----
__global__ __launch_bounds__(256) void scan_kernel(int* __restrict__ meta,
                                                   int* __restrict__ list) {
  const int tid = threadIdx.x;
  if (tid == 0) {
    int s = 0, n256 = 0, n128 = 0;
    for (int e = 0; e < E; ++e) {
      meta[24 + e] = s;
      const int cnt = meta[4 + e];
      const int tiles = (cnt + 255) >> 8;
      for (int i = 0; i < tiles; ++i) {
        meta[64 + n256]  = e;
        meta[104 + n256] = s + i * 256;
        ++n256;
        meta[144 + n128] = e; meta[224 + n128] = s + i * 256;       ++n128;
        meta[144 + n128] = e; meta[224 + n128] = s + i * 256 + 128; ++n128;
      }
      s += tiles << 8;
    }
    meta[32] = s;      // total padded rows
    meta[20] = n256;   // 256-row tiles
    meta[21] = n128;   // 128-row tiles
  }
  for (int i = tid; i < MAXROWS; i += 256) list[i] = 0;  // pad rows -> token 0
}

// ---- scatter token ids into per-expert padded lists ----
__global__ __launch_bounds__(256) void scatter_kernel(int* __restrict__ meta,
                                                      const int* __restrict__ topk,
                                                      int* __restrict__ list,
                                                      int* __restrict__ tokpos) {
  const int t = blockIdx.x * 256 + threadIdx.x;
  if (t >= TOK) return;
#pragma unroll
  for (int k = 0; k < 2; ++k) {
    const int e = topk[2 * t + k];
    const int p = atomicAdd(&meta[12 + e], 1);
    const int g = meta[24 + e] + p;
    list[g] = t;
    tokpos[2 * t + k] = g;
  }
}

// ============================================================================
// 8-phase 256-geometry pipeline (T2+T3+T4+T5) — shared by both gate+up kernels.
// Tile: 256 A-rows x 128 hmid cols; B-tile = 256 rows = [gate(128) | up(128)].
// 8 waves (wm 0..1 x wn 0..3), strip-interleaved; gate/up pair in-wave.
// vmcnt(4) at P4/P8 (2 half-tiles in flight); never 0 except peeled last iter.
// ============================================================================
#define GU_BAR_   __builtin_amdgcn_s_barrier()
#define GU_LGKM0_ { asm volatile("s_waitcnt lgkmcnt(0)" ::: "memory"); \
                    __builtin_amdgcn_sched_barrier(0); }
#define GU_VM4_   asm volatile("s_waitcnt vmcnt(4)" ::: "memory")
#define GU_VM0_   asm volatile("s_waitcnt vmcnt(0)" ::: "memory")

#define LDA_(p, mh) { _Pragma("unroll") for (int q2 = 0; q2 < 4; ++q2) { \
  _Pragma("unroll") for (int ks = 0; ks < 2; ++ks) { \
    const int row_ = 32 * (4 * (mh) + q2) + 16 * wm + lm; \
    a[q2][ks] = *(const bf16x8*)&ldsA[(p) * 16384 + row_ * 64 + \
                                      (((ks * 4 + quad) ^ (lm & 7)) * 8)]; } } }

#define LDB_(p, nh) { _Pragma("unroll") for (int nt2 = 0; nt2 < 2; ++nt2) { \
  _Pragma("unroll") for (int ks = 0; ks < 2; ++ks) { \
    const int row_ = 16 * (wn + 4 * (2 * (nh) + nt2)) + lm; \
    bb[nh][nt2][ks] = *(const bf16x8*)&ldsB[(p) * 16384 + row_ * 64 + \
                                            (((ks * 4 + quad) ^ (lm & 7)) * 8)]; } } }

#define MFMA_(mh, nh) { __builtin_amdgcn_s_setprio(1); \
  _Pragma("unroll") for (int q2 = 0; q2 < 4; ++q2) \
  _Pragma("unroll") for (int nt2 = 0; nt2 < 2; ++nt2) \
  _Pragma("unroll") for (int ks = 0; ks < 2; ++ks) \
    acc[4 * (mh) + q2][2 * (nh) + nt2] = __builtin_amdgcn_mfma_f32_16x16x32_bf16( \
      a[q2][ks], bb[nh][nt2][ks], acc[4 * (mh) + q2][2 * (nh) + nt2], 0, 0, 0); \
  __builtin_amdgcn_s_setprio(0); }

// K-loop body shared by both kernels; STA/STB are lambdas (kt, half).
#define GU_PIPELINE_(STA, STB) \
  STA(0, 0); STB(0, 0); STB(0, 1); STA(0, 1); \
  STB(1, 1); STA(1, 1); \
  GU_VM4_; GU_BAR_; \
  for (int i = 0; i < (H / 128) - 1; ++i) { \
    const int t0 = 2 * i, t1 = 2 * i + 1; \
    LDA_(0, 0); LDB_(0, 0); STA(t1, 0); \
    GU_BAR_; GU_LGKM0_; MFMA_(0, 0); GU_BAR_; \
    LDB_(0, 1); STB(t1, 0); \
    GU_BAR_; GU_LGKM0_; MFMA_(0, 1); GU_BAR_; \
    LDA_(0, 1); STA(t0 + 2, 0); \
    GU_BAR_; GU_LGKM0_; MFMA_(1, 1); GU_BAR_; \
    STB(t0 + 2, 0); GU_VM4_; \
    GU_BAR_; GU_LGKM0_; MFMA_(1, 0); GU_BAR_; \
    LDA_(1, 0); LDB_(1, 0); STB(t0 + 2, 1); \
    GU_BAR_; GU_LGKM0_; MFMA_(0, 0); GU_BAR_; \
    LDB_(1, 1); STA(t0 + 2, 1); \
    GU_BAR_; GU_LGKM0_; MFMA_(0, 1); GU_BAR_; \
    LDA_(1, 1); STB(t1 + 2, 1); \
    GU_BAR_; GU_LGKM0_; MFMA_(1, 1); GU_BAR_; \
    STA(t1 + 2, 1); GU_VM4_; \
    GU_BAR_; GU_LGKM0_; MFMA_(1, 0); GU_BAR_; \
  } \
  { \
    const int t1 = H / 64 - 1; \
    LDA_(0, 0); LDB_(0, 0); STA(t1, 0); \
    GU_BAR_; GU_LGKM0_; MFMA_(0, 0); GU_BAR_; \
    LDB_(0, 1); STB(t1, 0); \
    GU_BAR_; GU_LGKM0_; MFMA_(0, 1); GU_BAR_; \
    LDA_(0, 1); \
    GU_BAR_; GU_LGKM0_; MFMA_(1, 1); GU_BAR_; \
    GU_VM0_; \
    GU_BAR_; GU_LGKM0_; MFMA_(1, 0); GU_BAR_; \
    LDA_(1, 0); LDB_(1, 0); \
    GU_BAR_; GU_LGKM0_; MFMA_(0, 0); GU_BAR_; \
    LDB_(1, 1); \
    GU_BAR_; GU_LGKM0_; MFMA_(0, 1); GU_BAR_; \
    LDA_(1, 1); \
    GU_BAR_; GU_LGKM0_; MFMA_(1, 1); GU_BAR_; \
    MFMA_(1, 0); \
  }

__global__ __launch_bounds__(512, 2) void gateup_shared_kernel(
    const void* __restrict__ xo_,  const unsigned short* __restrict__ cx,
    const void* __restrict__ sgo_, const unsigned short* __restrict__ csgw,
    const void* __restrict__ suo_, const unsigned short* __restrict__ csuw,
    unsigned short* __restrict__ hmid_sh, const int* __restrict__ meta)
{
  extern __shared__ unsigned short lds[];
  unsigned short* ldsA = lds;             // [2][256*64] bf16 (64 KiB)
  unsigned short* ldsB = lds + 32768;     // [2][256*64] bf16 (64 KiB)

  const int bfmode = meta[0];
  const unsigned short* x  = bfmode ? (const unsigned short*)xo_  : cx;
  const unsigned short* gw = bfmode ? (const unsigned short*)sgo_ : csgw;
  const unsigned short* uw = bfmode ? (const unsigned short*)suo_ : csuw;

  const int tid = threadIdx.x;
  const int l = tid & 63, w = tid >> 6;
  const int wm = w >> 2, wn = w & 3;
  const int quad = l >> 4, lm = l & 15;
  const int m0 = blockIdx.x * 256;
  const int jb = blockIdx.y * 128;

  const unsigned short* gB = gw + (size_t)jb * H;
  const unsigned short* uB = uw + (size_t)jb * H;

  const int sr0 = tid >> 3,         sc0 = tid & 7;
  const int sr1 = (tid + 512) >> 3, sc1 = (tid + 512) & 7;
  const int scc0 = sc0 ^ (sr0 & 7), scc1 = sc1 ^ (sr1 & 7);
  const int sd0 = tid * 8, sd1 = (tid + 512) * 8;

  auto stA = [&](int kt, int half) {
    unsigned short* d = ldsA + (kt & 1) * 16384 + half * 8192;
    const unsigned short* s = x + (size_t)(m0 + half * 128) * H + kt * 64;
    gll16(s + (size_t)sr0 * H + scc0 * 8, d + sd0);
    gll16(s + (size_t)sr1 * H + scc1 * 8, d + sd1);
  };
  auto stB = [&](int kt, int half) {
    unsigned short* d = ldsB + (kt & 1) * 16384 + half * 8192;
    const unsigned short* s = (half ? uB : gB) + kt * 64;
    gll16(s + (size_t)sr0 * H + scc0 * 8, d + sd0);
    gll16(s + (size_t)sr1 * H + scc1 * 8, d + sd1);
  };

  f32x4 acc[8][4] = {};
  bf16x8 a[4][2];
  bf16x8 bb[2][2][2];

  GU_PIPELINE_(stA, stB);

  // epilogue: gate (nt 0,1) pairs with up (nt 2,3) in-wave, in-register
#pragma unroll
  for (int mt = 0; mt < 8; ++mt) {
    const int trow = m0 + 32 * mt + 16 * wm + quad * 4;
#pragma unroll
    for (int ntp = 0; ntp < 2; ++ntp) {
      const int col = jb + wn * 16 + ntp * 64 + lm;
#pragma unroll
      for (int rr = 0; rr < 4; ++rr) {
        const float g = acc[mt][ntp][rr];
        const float u = acc[mt][ntp + 2][rr];
        const float hm = (g / (1.f + expf(-g))) * u;
        hmid_sh[(size_t)(trow + rr) * ISD + col] = f2bf(hm);
      }
    }
  }
}

// ---- routed gate+up, 8-phase 256-geometry with gathered A rows ----
// grid: x = 256-row tile (MAXT256, early-exit), y = IDIM/128 = 8
__global__ __launch_bounds__(512, 2) void gateup_routed_kernel(
    const void* __restrict__ xo_,  const unsigned short* __restrict__ cx,
    const void* __restrict__ gwo_, const unsigned short* __restrict__ cgw,
    const void* __restrict__ uwo_, const unsigned short* __restrict__ cuw,
    const float* __restrict__ scale, const int* __restrict__ list,
    unsigned short* __restrict__ hmid_r, const int* __restrict__ meta)
{
  if ((int)blockIdx.x >= meta[20]) return;
  extern __shared__ unsigned short lds[];
  unsigned short* ldsA = lds;
  unsigned short* ldsB = lds + 32768;

  const int bfmode = meta[0];
  const unsigned short* x      = bfmode ? (const unsigned short*)xo_  : cx;
  const unsigned short* gate_w = bfmode ? (const unsigned short*)gwo_ : cgw;
  const unsigned short* up_w   = bfmode ? (const unsigned short*)uwo_ : cuw;

  const int tid = threadIdx.x;
  const int l = tid & 63, w = tid >> 6;
  const int wm = w >> 2, wn = w & 3;
  const int quad = l >> 4, lm = l & 15;
  const int e    = meta[64 + blockIdx.x];
  const int base = meta[104 + blockIdx.x];
  const int jb   = blockIdx.y * 128;

  const unsigned short* gB = gate_w + ((size_t)e * IDIM + jb) * H;
  const unsigned short* uB = up_w   + ((size_t)e * IDIM + jb) * H;

  const int sr0 = tid >> 3,         sc0 = tid & 7;
  const int sr1 = (tid + 512) >> 3, sc1 = (tid + 512) & 7;
  const int scc0 = sc0 ^ (sr0 & 7), scc1 = sc1 ^ (sr1 & 7);
  const int sd0 = tid * 8, sd1 = (tid + 512) * 8;

  // gathered token ids for this thread's staged A rows (constant over K)
  int tokh[2][2];
#pragma unroll
  for (int h = 0; h < 2; ++h) {
    tokh[h][0] = list[base + h * 128 + sr0];
    tokh[h][1] = list[base + h * 128 + sr1];
  }

  auto stA = [&](int kt, int half) {
    unsigned short* d = ldsA + (kt & 1) * 16384 + half * 8192;
    gll16(x + (size_t)tokh[half][0] * H + kt * 64 + scc0 * 8, d + sd0);
    gll16(x + (size_t)tokh[half][1] * H + kt * 64 + scc1 * 8, d + sd1);
  };
  auto stB = [&](int kt, int half) {
    unsigned short* d = ldsB + (kt & 1) * 16384 + half * 8192;
    const unsigned short* s = (half ? uB : gB) + kt * 64;
    gll16(s + (size_t)sr0 * H + scc0 * 8, d + sd0);
    gll16(s + (size_t)sr1 * H + scc1 * 8, d + sd1);
  };

  f32x4 acc[8][4] = {};
  bf16x8 a[4][2];
  bf16x8 bb[2][2][2];

  GU_PIPELINE_(stA, stB);

  // epilogue: scale expert inputs, silu(g*s)*(u*s), scatter to padded hmid_r
#pragma unroll
  for (int mt = 0; mt < 8; ++mt) {
    const int rloc = 32 * mt + 16 * wm + quad * 4;
#pragma unroll
    for (int rr = 0; rr < 4; ++rr) {
      const int gpos = base + rloc + rr;
      const float s = scale[(size_t)list[gpos] * E + e];
#pragma unroll
      for (int ntp = 0; ntp < 2; ++ntp) {
        const int col = jb + wn * 16 + ntp * 64 + lm;
        const float g = acc[mt][ntp][rr] * s;
        const float u = acc[mt][ntp + 2][rr] * s;
        const float hm = (g / (1.f + expf(-g))) * u;
        hmid_r[(size_t)gpos * IDIM + col] = f2bf(hm);
      }
    }
  }
}

// ---- routed down: dbuf[p,:] = hmid_r[p,:] . down_w[e]^T  (fp32 out) ----
// grid: x = out-col-tile (H/128 = 16, fastest), y = 128-row tile (early-exit)
__global__ __launch_bounds__(256) void down_routed_kernel(
    const unsigned short* __restrict__ hmid_r,
    const void* __restrict__ dwo_, const unsigned short* __restrict__ cdw,
    float* __restrict__ dbuf, const int* __restrict__ meta)
{
  if ((int)blockIdx.y >= meta[21]) return;
  const int bfmode = meta[0];
  const unsigned short* down_w = bfmode ? (const unsigned short*)dwo_ : cdw;

  __shared__ __attribute__((aligned(16))) unsigned short As[128 * 64];
  __shared__ __attribute__((aligned(16))) unsigned short Bs[128 * 64];

  const int tid = threadIdx.x;
  const int l = tid & 63, w = tid >> 6;
  const int e    = meta[144 + blockIdx.y];
  const int base = meta[224 + blockIdx.y];
  const int n0 = blockIdx.x * 128;

  const unsigned short* Bbase = down_w + ((size_t)e * H + n0) * IDIM;

  f32x4 acc[4][4] = {};
  const int wm = (w >> 1) * 64;
  const int wn = (w & 1) * 64;
  const int quad = l >> 4, lm = l & 15;

  for (int k0 = 0; k0 < IDIM; k0 += 64) {
#pragma unroll
    for (int j = 0; j < 4; ++j) {
      const int g = j * 256 + tid;
      const int r = g >> 3, c = g & 7;
      const int cc = c ^ (r & 7);
      gll16(hmid_r + (size_t)(base + r) * IDIM + k0 + cc * 8, &As[g * 8]);
    }
#pragma unroll
    for (int j = 0; j < 4; ++j) {
      const int g = j * 256 + tid;
      const int r = g >> 3, c = g & 7;
      const int cc = c ^ (r & 7);
      gll16(Bbase + (size_t)r * IDIM + k0 + cc * 8, &Bs[g * 8]);
    }
    __syncthreads();
#pragma unroll
    for (int ks = 0; ks < 64; ks += 32) {
      const int kc  = (ks >> 3) + quad;
      const int csw = (kc ^ (lm & 7)) * 8;
      bf16x8 a[4], b[4];
#pragma unroll
      for (int mt = 0; mt < 4; ++mt)
        a[mt] = *(const bf16x8*)&As[(wm + mt * 16 + lm) * 64 + csw];
#pragma unroll
      for (int nt = 0; nt < 4; ++nt)
        b[nt] = *(const bf16x8*)&Bs[(wn + nt * 16 + lm) * 64 + csw];
#pragma unroll
      for (int mt = 0; mt < 4; ++mt)
#pragma unroll
        for (int nt = 0; nt < 4; ++nt)
          acc[mt][nt] = __builtin_amdgcn_mfma_f32_16x16x32_bf16(a[mt], b[nt], acc[mt][nt], 0, 0, 0);
    }
    __syncthreads();
  }

#pragma unroll
  for (int mt = 0; mt < 4; ++mt)
#pragma unroll
    for (int nt = 0; nt < 4; ++nt)
#pragma unroll
      for (int r = 0; r < 4; ++r) {
        const int row = wm + mt * 16 + quad * 4 + r;
        const int n   = n0 + wn + nt * 16 + lm;
        dbuf[(size_t)(base + row) * H + n] = acc[mt][nt][r];
      }
}

// ---- shared down + gather-add of the 2 routed contributions ----
// grid: x = out-col-tile (16, fastest), y = token-tile (32)
__global__ __launch_bounds__(256) void down_shared_kernel(
    const unsigned short* __restrict__ hmid_sh,
    const void* __restrict__ sdwo_, const unsigned short* __restrict__ csdw,
    const float* __restrict__ dbuf, const int* __restrict__ tokpos,
    void* __restrict__ out, const int* __restrict__ meta)
{
  const int bfmode = meta[0];
  const unsigned short* sdown_w = bfmode ? (const unsigned short*)sdwo_ : csdw;

  __shared__ __attribute__((aligned(16))) unsigned short As[128 * 64];
  __shared__ __attribute__((aligned(16))) unsigned short Bs[128 * 64];

  const int tid = threadIdx.x;
  const int l = tid & 63, w = tid >> 6;
  const int m0 = blockIdx.y * 128;
  const int n0 = blockIdx.x * 128;

  f32x4 acc[4][4] = {};
  const int wm = (w >> 1) * 64;
  const int wn = (w & 1) * 64;
  const int quad = l >> 4, lm = l & 15;

  for (int k0 = 0; k0 < ISD; k0 += 64) {
#pragma unroll
    for (int j = 0; j < 4; ++j) {
      const int g = j * 256 + tid;
      const int r = g >> 3, c = g & 7;
      const int cc = c ^ (r & 7);
      gll16(hmid_sh + (size_t)(m0 + r) * ISD + k0 + cc * 8, &As[g * 8]);
    }
#pragma unroll
    for (int j = 0; j < 4; ++j) {
      const int g = j * 256 + tid;
      const int r = g >> 3, c = g & 7;
      const int cc = c ^ (r & 7);
      gll16(sdown_w + (size_t)(n0 + r) * ISD + k0 + cc * 8, &Bs[g * 8]);
    }
    __syncthreads();
#pragma unroll
    for (int ks = 0; ks < 64; ks += 32) {
      const int kc  = (ks >> 3) + quad;
      const int csw = (kc ^ (lm & 7)) * 8;
      bf16x8 a[4], b[4];
#pragma unroll
      for (int mt = 0; mt < 4; ++mt)
        a[mt] = *(const bf16x8*)&As[(wm + mt * 16 + lm) * 64 + csw];
#pragma unroll
      for (int nt = 0; nt < 4; ++nt)
        b[nt] = *(const bf16x8*)&Bs[(wn + nt * 16 + lm) * 64 + csw];
#pragma unroll
      for (int mt = 0; mt < 4; ++mt)
#pragma unroll
        for (int nt = 0; nt < 4; ++nt)
          acc[mt][nt] = __builtin_amdgcn_mfma_f32_16x16x32_bf16(a[mt], b[nt], acc[mt][nt], 0, 0, 0);
    }
    __syncthreads();
  }

  if (bfmode) {
    unsigned short* o = (unsigned short*)out;
#pragma unroll
    for (int mt = 0; mt < 4; ++mt)
#pragma unroll
      for (int r = 0; r < 4; ++r) {
        const int t = m0 + wm + mt * 16 + quad * 4 + r;
        const int p0 = tokpos[2 * t], p1 = tokpos[2 * t + 1];
#pragma unroll
        for (int nt = 0; nt < 4; ++nt) {
          const int n = n0 + wn + nt * 16 + lm;
          const float v = acc[mt][nt][r]
                        + dbuf[(size_t)p0 * H + n] + dbuf[(size_t)p1 * H + n];
          o[(size_t)t * H + n] = f2bf(v);
        }
      }
  } else {
    float* o = (float*)out;
#pragma unroll
    for (int mt = 0; mt < 4; ++mt)
#pragma unroll
      for (int r = 0; r < 4; ++r) {
        const int t = m0 + wm + mt * 16 + quad * 4 + r;
        const int p0 = tokpos[2 * t], p1 = tokpos[2 * t + 1];
#pragma unroll
        for (int nt = 0; nt < 4; ++nt) {
          const int n = n0 + wn + nt * 16 + lm;
          o[(size_t)t * H + n] = acc[mt][nt][r]
                               + dbuf[(size_t)p0 * H + n] + dbuf[(size_t)p1 * H + n];
        }
      }
  }
}

extern "C" void kernel_launch(void* const* d_in, const int* in_sizes, int n_in,
                              void* d_out, int out_size, void* d_ws, size_t ws_size,
                              hipStream_t stream) {
  const void* x   = d_in[0];
  const void* rw  = d_in[1];
  const void* gw  = d_in[2];
  const void* uw  = d_in[3];
  const void* dw  = d_in[4];
  const void* sgw = d_in[5];
  const void* suw = d_in[6];
  const void* sdw = d_in[7];

  char* wsb = (char*)d_ws;
  int*   meta   = (int*)wsb;                                  // 2048 B
  float* scale  = (float*)(wsb + 2048);                       // TOK*E fp32 (128 KiB)
  int*   topk   = (int*)(wsb + 2048 + (size_t)TOK * E * 4);   // TOK*2 (32 KiB)
  int*   list   = topk + (size_t)TOK * 2;                     // MAXROWS (40 KiB)
  int*   tokpos = list + MAXROWS;                             // TOK*2 (32 KiB)
  unsigned short* hmid_sh = (unsigned short*)(wsb + 262144);  // [TOK,ISD] bf16 (32 MiB)
  unsigned short* hmid_r  = hmid_sh + (size_t)TOK * ISD;      // [MAXROWS,IDIM] bf16 (20 MiB)
  unsigned short* cx   = hmid_r + (size_t)MAXROWS * IDIM;
  unsigned short* crw  = cx  + (size_t)TOK * H;
  unsigned short* cgw  = crw + (size_t)E * H;
  unsigned short* cuw  = cgw + (size_t)E * IDIM * H;
  unsigned short* cdw  = cuw + (size_t)E * IDIM * H;
  unsigned short* csgw = cdw + (size_t)E * H * IDIM;
  unsigned short* csuw = csgw + (size_t)ISD * H;
  unsigned short* csdw = csuw + (size_t)ISD * H;
  // routed-down fp32 buffer [MAXROWS,H] = 80.0 MB aliases cx..cuw (80.03 MB),
  // which are dead once the gate/up kernels complete; cdw/csdw are untouched.
  float* dbuf = (float*)cx;

  static int attr_set = 0;
  if (!attr_set) {
    hipFuncSetAttribute(reinterpret_cast<const void*>(gateup_shared_kernel),
                        hipFuncAttributeMaxDynamicSharedMemorySize, 131072);
    hipFuncSetAttribute(reinterpret_cast<const void*>(gateup_routed_kernel),
                        hipFuncAttributeMaxDynamicSharedMemorySize, 131072);
    attr_set = 1;
  }

  detect_kernel<<<1, 256, 0, stream>>>((const unsigned int*)x, meta);

  convert_all_kernel<<<2048, 256, 0, stream>>>(
      (const float*)x, (const float*)rw, (const float*)gw, (const float*)uw,
      (const float*)dw, (const float*)sgw, (const float*)suw, (const float*)sdw,
      cx, crw, cgw, cuw, cdw, csgw, csuw, csdw, meta);

  router_kernel<<<TOK, 256, 0, stream>>>(x, rw, d_out, scale, meta, topk);
  scan_kernel<<<1, 256, 0, stream>>>(meta, list);
  scatter_kernel<<<TOK / 256, 256, 0, stream>>>(meta, topk, list, tokpos);

  dim3 g1(TOK / 256, ISD / 128);      // 16 x 32, 512 threads, 128 KiB dynamic LDS
  gateup_shared_kernel<<<g1, 512, 131072, stream>>>(x, cx, sgw, csgw, suw, csuw,
                                                    hmid_sh, meta);

  dim3 g2(MAXT256, IDIM / 128);       // 40 x 8 (early-exit past nTiles256)
  gateup_routed_kernel<<<g2, 512, 131072, stream>>>(x, cx, gw, cgw, uw, cuw,
                                                    scale, list, hmid_r, meta);

  dim3 g3(H / 128, MAXT128);          // 16 x 80 (early-exit past nTiles128)
  down_routed_kernel<<<g3, 256, 0, stream>>>(hmid_r, dw, cdw, dbuf, meta);

  dim3 g4(H / 128, TOK / 128);        // 16 x 32
  down_shared_kernel<<<g4, 256, 0, stream>>>(hmid_sh, sdw, csdw, dbuf, tokpos, d_out, meta);
}